// Round 3
// baseline (3059.356 us; speedup 1.0000x reference)
//
#include <hip/hip_runtime.h>

// GRU: B=128, T=2048, H=128.
// Kernel 1 (gru_proj): xz/xr/xh = x @ W^T + b via bf16 MFMA 16x16x32.
//   xz,xr packed as 2x bf16 into d_out words (consumed then overwritten by h),
//   xh as bf16 into d_ws.
// Kernel 2 (gru_rec_mfma): 16 batches/block x 8 blocks, 8 waves. Each step:
//   z,r,h~ matvecs are [16,128]@[128,128] MFMA GEMMs; U fragments live in
//   VGPRs; h/rh tiles in 4KB LDS (XOR-swizzled vs 16-way bank conflict);
//   2 lgkmcnt-only barriers/step (vmcnt never drained in loop -> prefetch
//   and h-stores stay in flight). h recurrent path is fp32 in registers.

#define T_LEN 2048
#define H_DIM 128

typedef __attribute__((ext_vector_type(8))) __bf16 bf16x8;
typedef __attribute__((ext_vector_type(4))) float f32x4;

// raw barrier: drains LDS ops (cross-wave visibility) but NOT vmcnt. [m201]
#define BARRIER() asm volatile("s_waitcnt lgkmcnt(0)\n\ts_barrier" ::: "memory")

__device__ __forceinline__ unsigned short f2bf_bits(float f){
  __bf16 b = (__bf16)f;                     // fptrunc, RNE
  return __builtin_bit_cast(unsigned short, b);
}
__device__ __forceinline__ float bf2f(unsigned short s){
  unsigned int u = ((unsigned int)s) << 16;
  return __builtin_bit_cast(float, u);
}
__device__ __forceinline__ float sigm(float x){
  return 1.0f / (1.0f + exp2f(-1.4426950408889634f * x));
}
__device__ __forceinline__ float tanh_fast(float x){
  float e = exp2f(2.8853900817779268f * x);   // e^(2x); inf-safe
  return 1.0f - 2.0f / (e + 1.0f);
}

// ---------------- projection GEMM (unchanged, verified) ----------------

__device__ __forceinline__ void stage_mat128(const float* __restrict__ src,
                                             __bf16 (*dst)[136], int tid){
  #pragma unroll
  for (int rep = 0; rep < 8; ++rep){
    int fi = rep * 2048 + tid * 4;
    float4 v = *reinterpret_cast<const float4*>(src + fi);
    int m = fi >> 7;
    int k = fi & 127;
    unsigned long long pk =
        (unsigned long long)f2bf_bits(v.x)
      | ((unsigned long long)f2bf_bits(v.y) << 16)
      | ((unsigned long long)f2bf_bits(v.z) << 32)
      | ((unsigned long long)f2bf_bits(v.w) << 48);
    *reinterpret_cast<unsigned long long*>(&dst[m][k]) = pk;
  }
}

__global__ __launch_bounds__(512, 2) void gru_proj(
    const float* __restrict__ x,
    const float* __restrict__ Wz, const float* __restrict__ Wr, const float* __restrict__ Wh,
    const float* __restrict__ bz, const float* __restrict__ br, const float* __restrict__ bh,
    unsigned int* __restrict__ out_zr, unsigned short* __restrict__ out_h)
{
  __shared__ __bf16 xs[128][136];
  __shared__ __bf16 wsh[3][128][136];

  const int tid = threadIdx.x;
  const long Mbase = (long)blockIdx.x * 128;

  stage_mat128(x + Mbase * H_DIM, xs, tid);
  stage_mat128(Wz, wsh[0], tid);
  stage_mat128(Wr, wsh[1], tid);
  stage_mat128(Wh, wsh[2], tid);
  __syncthreads();

  const int w  = tid >> 6, l = tid & 63;
  const int ml = l & 15;
  const int kl = (l >> 4) * 8;
  const int n  = w * 16 + ml;

  bf16x8 bfr[3][4];
  #pragma unroll
  for (int g = 0; g < 3; ++g)
    #pragma unroll
    for (int kk = 0; kk < 4; ++kk)
      bfr[g][kk] = *reinterpret_cast<const bf16x8*>(&wsh[g][n][kk * 32 + kl]);

  const float bzv = bz[n], brv = br[n], bhv = bh[n];

  f32x4 acc[8][3];
  #pragma unroll
  for (int mt = 0; mt < 8; ++mt)
    #pragma unroll
    for (int g = 0; g < 3; ++g)
      acc[mt][g] = (f32x4){0.f, 0.f, 0.f, 0.f};

  #pragma unroll
  for (int mt = 0; mt < 8; ++mt){
    #pragma unroll
    for (int kk = 0; kk < 4; ++kk){
      bf16x8 a = *reinterpret_cast<const bf16x8*>(&xs[mt * 16 + ml][kk * 32 + kl]);
      acc[mt][0] = __builtin_amdgcn_mfma_f32_16x16x32_bf16(a, bfr[0][kk], acc[mt][0], 0, 0, 0);
      acc[mt][1] = __builtin_amdgcn_mfma_f32_16x16x32_bf16(a, bfr[1][kk], acc[mt][1], 0, 0, 0);
      acc[mt][2] = __builtin_amdgcn_mfma_f32_16x16x32_bf16(a, bfr[2][kk], acc[mt][2], 0, 0, 0);
    }
  }

  #pragma unroll
  for (int mt = 0; mt < 8; ++mt){
    #pragma unroll
    for (int p = 0; p < 4; ++p){
      long row = Mbase + mt * 16 + (l >> 4) * 4 + p;
      float vz = acc[mt][0][p] + bzv;
      float vr = acc[mt][1][p] + brv;
      float vh = acc[mt][2][p] + bhv;
      unsigned int word = (unsigned int)f2bf_bits(vz)
                        | (((unsigned int)f2bf_bits(vr)) << 16);
      out_zr[row * H_DIM + n] = word;
      out_h [row * H_DIM + n] = f2bf_bits(vh);
    }
  }
}

// ---------------- recurrence: batched MFMA ----------------
// LDS h/rh tiles: [16 rows][128 units] bf16, element index swizzled
// idx = r*128 + (u ^ ((r&7)<<3))  -> conflict-free ds_read_b128 A-frags.

__device__ __forceinline__ bf16x8 ld_u_frag(const float* p){
  float4 a = *reinterpret_cast<const float4*>(p);
  float4 b = *reinterpret_cast<const float4*>(p + 4);
  bf16x8 r;
  r[0]=(__bf16)a.x; r[1]=(__bf16)a.y; r[2]=(__bf16)a.z; r[3]=(__bf16)a.w;
  r[4]=(__bf16)b.x; r[5]=(__bf16)b.y; r[6]=(__bf16)b.z; r[7]=(__bf16)b.w;
  return r;
}

__device__ __forceinline__ void gru_step_mfma(
    int t, int row, int g8, int n,
    const bf16x8* ufz, const bf16x8* ufr, const bf16x8* ufh,
    __bf16* hbf, __bf16* rhbf,
    const unsigned int* xzr, const unsigned short* xh, float* out,
    const long* obase, const int* lenp,
    unsigned int* zrw, unsigned short* xhw,
    float* h_own, float* zgp)
{
  // ---- phase A: z,r GEMMs on h tile ----
  f32x4 az = (f32x4){0.f,0.f,0.f,0.f};
  f32x4 ar = (f32x4){0.f,0.f,0.f,0.f};
  #pragma unroll
  for (int kk = 0; kk < 4; ++kk){
    bf16x8 a = *reinterpret_cast<const bf16x8*>(
        &hbf[row * 128 + ((kk * 32 + g8 * 8) ^ ((row & 7) << 3))]);
    az = __builtin_amdgcn_mfma_f32_16x16x32_bf16(a, ufz[kk], az, 0, 0, 0);
    ar = __builtin_amdgcn_mfma_f32_16x16x32_bf16(a, ufr[kk], ar, 0, 0, 0);
  }
  #pragma unroll
  for (int p = 0; p < 4; ++p){
    float vz = az[p] + bf2f((unsigned short)(zrw[p] & 0xffffu));
    float vr = ar[p] + bf2f((unsigned short)(zrw[p] >> 16));
    float z = sigm(vz), r = sigm(vr);
    zgp[p] = z;
    float rh = r * h_own[p];
    int bl = g8 * 4 + p;
    rhbf[bl * 128 + (n ^ ((bl & 7) << 3))] = (__bf16)rh;
    int tt = t + 2 < T_LEN ? t + 2 : T_LEN - 1;       // refill for t+2
    zrw[p] = xzr[obase[p] + (long)tt * H_DIM];
  }
  BARRIER();                              // rh visible; vmcnt untouched

  // ---- phase B: candidate GEMM on rh tile ----
  f32x4 ah = (f32x4){0.f,0.f,0.f,0.f};
  #pragma unroll
  for (int kk = 0; kk < 4; ++kk){
    bf16x8 a = *reinterpret_cast<const bf16x8*>(
        &rhbf[row * 128 + ((kk * 32 + g8 * 8) ^ ((row & 7) << 3))]);
    ah = __builtin_amdgcn_mfma_f32_16x16x32_bf16(a, ufh[kk], ah, 0, 0, 0);
  }
  #pragma unroll
  for (int p = 0; p < 4; ++p){
    float hc = tanh_fast(ah[p] + bf2f(xhw[p]));
    float hn = h_own[p] + zgp[p] * (hc - h_own[p]);   // (1-z)h + z*hc
    h_own[p] = hn;
    int bl = g8 * 4 + p;
    hbf[bl * 128 + (n ^ ((bl & 7) << 3))] = (__bf16)hn;
    if (t < lenp[p])
      out[obase[p] + (long)t * H_DIM] = hn;           // fire-and-forget
    int tt = t + 2 < T_LEN ? t + 2 : T_LEN - 1;       // refill for t+2
    xhw[p] = xh[obase[p] + (long)tt * H_DIM];
  }
  BARRIER();                              // h' visible; vmcnt untouched
}

__global__ __launch_bounds__(512, 1) void gru_rec_mfma(
    const float* __restrict__ Uz, const float* __restrict__ Ur, const float* __restrict__ Uh,
    const int* __restrict__ lengths,
    const unsigned int* xzr,            // aliases `out` (packed bf16 xz|xr)
    const unsigned short* __restrict__ xh,
    float* out)
{
  __shared__ __align__(16) __bf16 hbf[16 * 128];
  __shared__ __align__(16) __bf16 rhbf[16 * 128];

  const int tid = threadIdx.x;
  const int w = tid >> 6, l = tid & 63;
  const int n   = w * 16 + (l & 15);    // owned unit (C col)
  const int g8  = l >> 4;               // k-slice / C row-block
  const int row = l & 15;               // A-frag row
  const int gblk = blockIdx.x;          // batch group: batches [16g, 16g+16)

  // U B-fragments in registers: 3 gates x 4 k-steps x 4 VGPR = 48 VGPRs
  bf16x8 ufz[4], ufr[4], ufh[4];
  #pragma unroll
  for (int kk = 0; kk < 4; ++kk){
    const int ko = kk * 32 + g8 * 8;
    ufz[kk] = ld_u_frag(Uz + n * H_DIM + ko);
    ufr[kk] = ld_u_frag(Ur + n * H_DIM + ko);
    ufh[kk] = ld_u_frag(Uh + n * H_DIM + ko);
  }

  // per-lane C ownership: batches bl = g8*4+p, unit n
  int  lenp[4];
  long obase[4];
  #pragma unroll
  for (int p = 0; p < 4; ++p){
    int b = gblk * 16 + g8 * 4 + p;
    lenp[p]  = lengths[b];
    obase[p] = (long)b * T_LEN * H_DIM + n;
  }
  int maxlen = 0;
  #pragma unroll
  for (int i = 0; i < 16; ++i){
    int L = lengths[gblk * 16 + i];
    maxlen = L > maxlen ? L : maxlen;
  }

  // zero h tile (h0 = 0)
  *reinterpret_cast<unsigned long long*>(&hbf[tid * 4]) = 0ull;
  float h_own[4] = {0.f, 0.f, 0.f, 0.f};
  float zgp[4]   = {0.f, 0.f, 0.f, 0.f};
  __syncthreads();

  // 2-deep prefetch, named register sets (compile-time indexed)
  unsigned int  zrA[4], zrB[4];
  unsigned short xhA[4], xhB[4];
  #pragma unroll
  for (int p = 0; p < 4; ++p){
    zrA[p] = xzr[obase[p]];
    xhA[p] = xh [obase[p]];
    zrB[p] = xzr[obase[p] + H_DIM];
    xhB[p] = xh [obase[p] + H_DIM];
  }

  int t = 0;
  for (; t + 1 < maxlen; t += 2){
    gru_step_mfma(t,   row, g8, n, ufz, ufr, ufh, hbf, rhbf, xzr, xh, out,
                  obase, lenp, zrA, xhA, h_own, zgp);
    gru_step_mfma(t+1, row, g8, n, ufz, ufr, ufh, hbf, rhbf, xzr, xh, out,
                  obase, lenp, zrB, xhB, h_own, zgp);
  }
  if (t < maxlen){
    gru_step_mfma(t,   row, g8, n, ufz, ufr, ufh, hbf, rhbf, xzr, xh, out,
                  obase, lenp, zrA, xhA, h_own, zgp);
  }

  // masked region: exact zeros for t >= len[b] (disjoint from predicated
  // h-stores -> no ordering needed vs in-flight stores)
  for (int i = 0; i < 16; ++i){
    int b = gblk * 16 + i;
    int L = lengths[b];
    long rbase = (long)b * T_LEN * H_DIM;
    for (long idx = (long)L * H_DIM + tid * 4; idx < (long)T_LEN * H_DIM; idx += 512 * 4){
      *reinterpret_cast<float4*>(out + rbase + idx) = make_float4(0.f, 0.f, 0.f, 0.f);
    }
  }
}

extern "C" void kernel_launch(void* const* d_in, const int* in_sizes, int n_in,
                              void* d_out, int out_size, void* d_ws, size_t ws_size,
                              hipStream_t stream){
  const float* x       = (const float*)d_in[0];
  const int*   lengths = (const int*)  d_in[1];
  const float* Wz = (const float*)d_in[2];
  const float* Uz = (const float*)d_in[3];
  const float* bz = (const float*)d_in[4];
  const float* Wr = (const float*)d_in[5];
  const float* Ur = (const float*)d_in[6];
  const float* br = (const float*)d_in[7];
  const float* Wh = (const float*)d_in[8];
  const float* Uh = (const float*)d_in[9];
  const float* bh = (const float*)d_in[10];

  unsigned int*   zr    = (unsigned int*)d_out;   // packed bf16 xz|xr, then h
  unsigned short* xhbuf = (unsigned short*)d_ws;  // bf16 xh

  gru_proj<<<dim3(2048), dim3(512), 0, stream>>>(x, Wz, Wr, Wh, bz, br, bh, zr, xhbuf);
  gru_rec_mfma<<<dim3(8), dim3(512), 0, stream>>>(Uz, Ur, Uh, lengths, zr, xhbuf, (float*)d_out);
}

// Round 4
// 1235.195 us; speedup vs baseline: 2.4768x; 2.4768x over previous
//
#include <hip/hip_runtime.h>

// GRU: B=128, T=2048, H=128.
// Kernel 1 (gru_proj): xz/xr/xh = x @ W^T + b via bf16 MFMA 16x16x32.
//   xz,xr packed as 2x bf16 into d_out words (consumed then overwritten by h),
//   xh as bf16 into d_ws.
// Kernel 2 (gru_rec_bcast): 1 batch/block x 128 blocks, 8 waves. Matvecs via
//   broadcast-A MFMA: all 16 A-rows = h, so each lane's acc[0] is the full
//   128-k dot for its unit u=16w+(l&15) -- k-reduce inside the MFMA, no
//   shuffles. Exchange h/rh as bf16[128] in LDS (cvt_pk+DPP pair -> packed
//   b32 writes, zero bank conflicts). 2 lgkm-only barriers/step; global
//   prefetch 2 steps deep + fire-and-forget h stores (vmcnt never drained).

#define T_LEN 2048
#define H_DIM 128

typedef __attribute__((ext_vector_type(8))) __bf16 bf16x8;
typedef __attribute__((ext_vector_type(4))) float f32x4;

// raw barrier: drains LDS ops (cross-wave visibility) but NOT vmcnt. [m201]
#define BARRIER() asm volatile("s_waitcnt lgkmcnt(0)\n\ts_barrier" ::: "memory")

__device__ __forceinline__ unsigned short f2bf_bits(float f){
  __bf16 b = (__bf16)f;                     // fptrunc, RNE
  return __builtin_bit_cast(unsigned short, b);
}
__device__ __forceinline__ float bf2f(unsigned short s){
  unsigned int u = ((unsigned int)s) << 16;
  return __builtin_bit_cast(float, u);
}
__device__ __forceinline__ float sigm(float x){
  return 1.0f / (1.0f + exp2f(-1.4426950408889634f * x));
}
__device__ __forceinline__ float tanh_fast(float x){
  float e = exp2f(2.8853900817779268f * x);   // e^(2x); inf-safe
  return 1.0f - 2.0f / (e + 1.0f);
}
// lane <- lane^1 value (quad_perm [1,0,3,2] = 0xB1), pure VALU
__device__ __forceinline__ float dpp_xor1(float x){
  int r = __builtin_amdgcn_update_dpp(0, __builtin_bit_cast(int, x),
                                      0xB1, 0xF, 0xF, true);
  return __builtin_bit_cast(float, r);
}
// pack two f32 -> bf16 pair in one instruction [T12, m240: no builtin]
__device__ __forceinline__ unsigned int cvt_pk_bf16(float lo, float hi){
  unsigned int d;
  asm("v_cvt_pk_bf16_f32 %0, %1, %2" : "=v"(d) : "v"(lo), "v"(hi));
  return d;
}

// ---------------- projection GEMM (unchanged, verified) ----------------

__device__ __forceinline__ void stage_mat128(const float* __restrict__ src,
                                             __bf16 (*dst)[136], int tid){
  #pragma unroll
  for (int rep = 0; rep < 8; ++rep){
    int fi = rep * 2048 + tid * 4;
    float4 v = *reinterpret_cast<const float4*>(src + fi);
    int m = fi >> 7;
    int k = fi & 127;
    unsigned long long pk =
        (unsigned long long)f2bf_bits(v.x)
      | ((unsigned long long)f2bf_bits(v.y) << 16)
      | ((unsigned long long)f2bf_bits(v.z) << 32)
      | ((unsigned long long)f2bf_bits(v.w) << 48);
    *reinterpret_cast<unsigned long long*>(&dst[m][k]) = pk;
  }
}

__global__ __launch_bounds__(512, 2) void gru_proj(
    const float* __restrict__ x,
    const float* __restrict__ Wz, const float* __restrict__ Wr, const float* __restrict__ Wh,
    const float* __restrict__ bz, const float* __restrict__ br, const float* __restrict__ bh,
    unsigned int* __restrict__ out_zr, unsigned short* __restrict__ out_h)
{
  __shared__ __bf16 xs[128][136];
  __shared__ __bf16 wsh[3][128][136];

  const int tid = threadIdx.x;
  const long Mbase = (long)blockIdx.x * 128;

  stage_mat128(x + Mbase * H_DIM, xs, tid);
  stage_mat128(Wz, wsh[0], tid);
  stage_mat128(Wr, wsh[1], tid);
  stage_mat128(Wh, wsh[2], tid);
  __syncthreads();

  const int w  = tid >> 6, l = tid & 63;
  const int ml = l & 15;
  const int kl = (l >> 4) * 8;
  const int n  = w * 16 + ml;

  bf16x8 bfr[3][4];
  #pragma unroll
  for (int g = 0; g < 3; ++g)
    #pragma unroll
    for (int kk = 0; kk < 4; ++kk)
      bfr[g][kk] = *reinterpret_cast<const bf16x8*>(&wsh[g][n][kk * 32 + kl]);

  const float bzv = bz[n], brv = br[n], bhv = bh[n];

  f32x4 acc[8][3];
  #pragma unroll
  for (int mt = 0; mt < 8; ++mt)
    #pragma unroll
    for (int g = 0; g < 3; ++g)
      acc[mt][g] = (f32x4){0.f, 0.f, 0.f, 0.f};

  #pragma unroll
  for (int mt = 0; mt < 8; ++mt){
    #pragma unroll
    for (int kk = 0; kk < 4; ++kk){
      bf16x8 a = *reinterpret_cast<const bf16x8*>(&xs[mt * 16 + ml][kk * 32 + kl]);
      acc[mt][0] = __builtin_amdgcn_mfma_f32_16x16x32_bf16(a, bfr[0][kk], acc[mt][0], 0, 0, 0);
      acc[mt][1] = __builtin_amdgcn_mfma_f32_16x16x32_bf16(a, bfr[1][kk], acc[mt][1], 0, 0, 0);
      acc[mt][2] = __builtin_amdgcn_mfma_f32_16x16x32_bf16(a, bfr[2][kk], acc[mt][2], 0, 0, 0);
    }
  }

  #pragma unroll
  for (int mt = 0; mt < 8; ++mt){
    #pragma unroll
    for (int p = 0; p < 4; ++p){
      long row = Mbase + mt * 16 + (l >> 4) * 4 + p;
      float vz = acc[mt][0][p] + bzv;
      float vr = acc[mt][1][p] + brv;
      float vh = acc[mt][2][p] + bhv;
      unsigned int word = (unsigned int)f2bf_bits(vz)
                        | (((unsigned int)f2bf_bits(vr)) << 16);
      out_zr[row * H_DIM + n] = word;
      out_h [row * H_DIM + n] = f2bf_bits(vh);
    }
  }
}

// ---------------- recurrence: broadcast-A MFMA, 1 batch/block ----------------

__device__ __forceinline__ bf16x8 ld_u_frag(const float* p){
  float4 a = *reinterpret_cast<const float4*>(p);
  float4 b = *reinterpret_cast<const float4*>(p + 4);
  bf16x8 r;
  r[0]=(__bf16)a.x; r[1]=(__bf16)a.y; r[2]=(__bf16)a.z; r[3]=(__bf16)a.w;
  r[4]=(__bf16)b.x; r[5]=(__bf16)b.y; r[6]=(__bf16)b.z; r[7]=(__bf16)b.w;
  return r;
}

#define MFMA(A, B, C) __builtin_amdgcn_mfma_f32_16x16x32_bf16(A, B, C, 0, 0, 0)

__device__ __forceinline__ void gru_step_bc(
    int t, int ub, int g8, int l, int w,
    const bf16x8* ufz, const bf16x8* ufr, const bf16x8* ufh,
    __bf16* hx, __bf16* rhx,
    const unsigned int* xzr, const unsigned short* xh, float* out,
    unsigned int& zrw, unsigned short& xhw, float& h_own, float& zg)
{
  const f32x4 zero = (f32x4){0.f, 0.f, 0.f, 0.f};
  const int tp = (t + 2 < T_LEN) ? t + 2 : T_LEN - 1;   // prefetch slot
  const bool wr = ((l & 1) == 0) & (l < 16);            // pair-writer lanes

  // ---- phase A: z,r dots via broadcast-A MFMA ----
  bf16x8 a0 = *reinterpret_cast<const bf16x8*>(&hx[      g8 * 8]);
  bf16x8 a1 = *reinterpret_cast<const bf16x8*>(&hx[32  + g8 * 8]);
  bf16x8 a2 = *reinterpret_cast<const bf16x8*>(&hx[64  + g8 * 8]);
  bf16x8 a3 = *reinterpret_cast<const bf16x8*>(&hx[96  + g8 * 8]);
  f32x4 azA = MFMA(a0, ufz[0], zero);  f32x4 arA = MFMA(a0, ufr[0], zero);
  azA = MFMA(a1, ufz[1], azA);         arA = MFMA(a1, ufr[1], arA);
  f32x4 azB = MFMA(a2, ufz[2], zero);  f32x4 arB = MFMA(a2, ufr[2], zero);
  azB = MFMA(a3, ufz[3], azB);         arB = MFMA(a3, ufr[3], arB);

  float z = sigm(bf2f((unsigned short)(zrw & 0xffffu)) + azA[0] + azB[0]);
  float r = sigm(bf2f((unsigned short)(zrw >> 16))     + arA[0] + arB[0]);
  zg = z;
  float rh  = r * h_own;
  float rhn = dpp_xor1(rh);
  if (wr)
    *reinterpret_cast<unsigned int*>(&rhx[w * 16 + (l & 14)]) = cvt_pk_bf16(rh, rhn);
  zrw = xzr[ub + tp * H_DIM];                            // refill for t+2
  BARRIER();                                             // rh visible

  // ---- phase B: candidate dot on r*h ----
  bf16x8 b0 = *reinterpret_cast<const bf16x8*>(&rhx[      g8 * 8]);
  bf16x8 b1 = *reinterpret_cast<const bf16x8*>(&rhx[32  + g8 * 8]);
  bf16x8 b2 = *reinterpret_cast<const bf16x8*>(&rhx[64  + g8 * 8]);
  bf16x8 b3 = *reinterpret_cast<const bf16x8*>(&rhx[96  + g8 * 8]);
  f32x4 ahA = MFMA(b0, ufh[0], zero);
  ahA = MFMA(b1, ufh[1], ahA);
  f32x4 ahB = MFMA(b2, ufh[2], zero);
  ahB = MFMA(b3, ufh[3], ahB);

  float hc = tanh_fast(bf2f(xhw) + ahA[0] + ahB[0]);
  float hn = h_own + zg * (hc - h_own);                  // (1-z)h + z*hc
  h_own = hn;
  float hnn = dpp_xor1(hn);
  if (wr)
    *reinterpret_cast<unsigned int*>(&hx[w * 16 + (l & 14)]) = cvt_pk_bf16(hn, hnn);
  if (l < 16)
    out[ub + t * H_DIM] = hn;                            // fire-and-forget
  xhw = xh[ub + tp * H_DIM];                             // refill for t+2
  BARRIER();                                             // h' visible
}

__global__ __launch_bounds__(512, 1) void gru_rec_bcast(
    const float* __restrict__ Uz, const float* __restrict__ Ur, const float* __restrict__ Uh,
    const int* __restrict__ lengths,
    const unsigned int* xzr,            // aliases `out` (packed bf16 xz|xr)
    const unsigned short* __restrict__ xh,
    float* out)
{
  __shared__ __align__(16) __bf16 hx[H_DIM];
  __shared__ __align__(16) __bf16 rhx[H_DIM];

  const int tid = threadIdx.x;
  const int w = tid >> 6, l = tid & 63;
  const int g8 = l >> 4;                // k-slice within each 32-k block
  const int u  = w * 16 + (l & 15);     // owned unit (C col)
  const int b  = blockIdx.x;
  const int len = lengths[b];

  // U B-fragments: 3 gates x 4 k-steps x 4 VGPR = 48 VGPRs
  bf16x8 ufz[4], ufr[4], ufh[4];
  #pragma unroll
  for (int kk = 0; kk < 4; ++kk){
    const int ko = kk * 32 + g8 * 8;
    ufz[kk] = ld_u_frag(Uz + u * H_DIM + ko);
    ufr[kk] = ld_u_frag(Ur + u * H_DIM + ko);
    ufh[kk] = ld_u_frag(Uh + u * H_DIM + ko);
  }

  if (tid < 64) reinterpret_cast<unsigned int*>(hx)[tid & 31] = 0u; // h0 = 0 (first 32 lanes cover it; harmless dup)
  float h_own = 0.f, zg = 0.f;
  __syncthreads();

  const int ub = b * (T_LEN * H_DIM) + u;   // element offset of (b, t=0, u)

  // 2-deep prefetch, named regs
  unsigned int  zrA, zrB;
  unsigned short xhA, xhB;
  zrA = xzr[ub];             xhA = xh[ub];
  zrB = xzr[ub + H_DIM];     xhB = xh[ub + H_DIM];

  int t = 0;
  for (; t + 1 < len; t += 2){
    gru_step_bc(t,   ub, g8, l, w, ufz, ufr, ufh, hx, rhx, xzr, xh, out, zrA, xhA, h_own, zg);
    gru_step_bc(t+1, ub, g8, l, w, ufz, ufr, ufh, hx, rhx, xzr, xh, out, zrB, xhB, h_own, zg);
  }
  if (t < len){
    gru_step_bc(t,   ub, g8, l, w, ufz, ufr, ufh, hx, rhx, xzr, xh, out, zrA, xhA, h_own, zg);
  }

  // masked region: exact zeros for t >= len (disjoint from h-stores)
  const long base = (long)b * (T_LEN * H_DIM);
  for (long i = (long)len * H_DIM + tid * 4; i < (long)T_LEN * H_DIM; i += 512 * 4){
    *reinterpret_cast<float4*>(out + base + i) = make_float4(0.f, 0.f, 0.f, 0.f);
  }
}

extern "C" void kernel_launch(void* const* d_in, const int* in_sizes, int n_in,
                              void* d_out, int out_size, void* d_ws, size_t ws_size,
                              hipStream_t stream){
  const float* x       = (const float*)d_in[0];
  const int*   lengths = (const int*)  d_in[1];
  const float* Wz = (const float*)d_in[2];
  const float* Uz = (const float*)d_in[3];
  const float* bz = (const float*)d_in[4];
  const float* Wr = (const float*)d_in[5];
  const float* Ur = (const float*)d_in[6];
  const float* br = (const float*)d_in[7];
  const float* Wh = (const float*)d_in[8];
  const float* Uh = (const float*)d_in[9];
  const float* bh = (const float*)d_in[10];

  unsigned int*   zr    = (unsigned int*)d_out;   // packed bf16 xz|xr, then h
  unsigned short* xhbuf = (unsigned short*)d_ws;  // bf16 xh

  gru_proj<<<dim3(2048), dim3(512), 0, stream>>>(x, Wz, Wr, Wh, bz, br, bh, zr, xhbuf);
  gru_rec_bcast<<<dim3(128), dim3(512), 0, stream>>>(Uz, Ur, Uh, lengths, zr, xhbuf, (float*)d_out);
}